// Round 1
// baseline (74.435 us; speedup 1.0000x reference)
//
#include <hip/hip_runtime.h>

#define HID 128
#define NN  256
#define BB  8
#define NCATS 64

// ---------------------------------------------------------------------------
// Wave-per-row LN reduction helper (row values a (lane), c (lane+64)).
// Returns mean and rsqrt(var+eps) to all 64 lanes of the wave.
__device__ inline void ln_stats(float a, float c, float& mean, float& rs) {
    float s = a + c;
    float q = a * a + c * c;
    #pragma unroll
    for (int m = 32; m; m >>= 1) {
        s += __shfl_xor(s, m);
        q += __shfl_xor(q, m);
    }
    mean = s * (1.0f / 128.0f);
    float var = q * (1.0f / 128.0f) - mean * mean;
    rs = rsqrtf(var + 1e-5f);
}

// ---------------------------------------------------------------------------
// Setup kernel:
//   blocks [0,256):   input MLP, 8 rows each  -> h0
//   blocks [256,264): normalize emb -> ne   (8 rows per block, wave per row)
//   blocks [264,296): pack edge_cat transposed -> catp[jb*256+i] (8 cats/entry)
__global__ __launch_bounds__(512) void k_setup(
    const float* __restrict__ x, const float* __restrict__ emb,
    const float* __restrict__ inW1, const float* __restrict__ inb1,
    const float* __restrict__ ing1, const float* __restrict__ inbt1,
    const float* __restrict__ inW2, const float* __restrict__ inb2,
    const float* __restrict__ ing2, const float* __restrict__ inbt2,
    const int* __restrict__ ecat,
    float* __restrict__ ne, uint2* __restrict__ catp, float* __restrict__ h0)
{
    __shared__ __align__(16) float sV[8][128];
    __shared__ __align__(16) float sH1[8][128];
    __shared__ __align__(16) float sA[4][8][128];

    const int blk = blockIdx.x;
    const int t = threadIdx.x;
    const int w = t >> 6, lane = t & 63;

    if (blk < 256) {
        const int row0 = blk * 8;
        // Linear(2->128): no reduction needed (CIN=2 inline)
        for (int item = t; item < 1024; item += 512) {
            int r = item >> 7, dd = item & 127;
            int row = row0 + r;
            float x0 = x[row * 2 + 0], x1 = x[row * 2 + 1];
            sV[r][dd] = fmaf(x0, inW1[dd], fmaf(x1, inW1[128 + dd], inb1[dd]));
        }
        __syncthreads();
        // LN1 + relu
        {
            float a = sV[w][lane], c = sV[w][lane + 64];
            float mean, rs; ln_stats(a, c, mean, rs);
            sH1[w][lane]      = fmaxf((a - mean) * rs * ing1[lane]      + inbt1[lane],      0.f);
            sH1[w][lane + 64] = fmaxf((c - mean) * rs * ing1[lane + 64] + inbt1[lane + 64], 0.f);
        }
        __syncthreads();
        // GEMM2 (128x128), k-split by 4
        {
            int dd = t & 127, ks = t >> 7;
            float acc[8] = {0.f, 0.f, 0.f, 0.f, 0.f, 0.f, 0.f, 0.f};
            for (int k = ks * 32; k < ks * 32 + 32; ++k) {
                float wv = inW2[k * 128 + dd];
                #pragma unroll
                for (int r = 0; r < 8; ++r) acc[r] = fmaf(sH1[r][k], wv, acc[r]);
            }
            #pragma unroll
            for (int r = 0; r < 8; ++r) sA[ks][r][dd] = acc[r];
        }
        __syncthreads();
        for (int item = t; item < 1024; item += 512) {
            int r = item >> 7, dd = item & 127;
            sV[r][dd] = inb2[dd] + sA[0][r][dd] + sA[1][r][dd] + sA[2][r][dd] + sA[3][r][dd];
        }
        __syncthreads();
        // LN2 -> h0
        {
            float a = sV[w][lane], c = sV[w][lane + 64];
            float mean, rs; ln_stats(a, c, mean, rs);
            int row = row0 + w;
            h0[row * HID + lane]      = (a - mean) * rs * ing2[lane]      + inbt2[lane];
            h0[row * HID + lane + 64] = (c - mean) * rs * ing2[lane + 64] + inbt2[lane + 64];
        }
    } else if (blk < 264) {
        // normalize emb rows -> ne
        int r = (blk - 256) * 8 + w;
        float a = emb[r * 128 + lane], c = emb[r * 128 + lane + 64];
        float q = a * a + c * c;
        #pragma unroll
        for (int m = 32; m; m >>= 1) q += __shfl_xor(q, m);
        float cn = sqrtf(q);
        if (cn == 0.f) cn = 1e-8f;
        float sc = fminf(1.0f, 1.0f / cn);
        ne[r * 128 + lane]      = a * sc;
        ne[r * 128 + lane + 64] = c * sc;
    } else {
        // pack transposed categories: catp[jb*256+i] = cats of (i, jb*8 .. jb*8+7)
        int jb = blk - 264;
        if (t < 256) {
            int i = t;
            const int* p = ecat + i * NN + jb * 8;
            int4 c0 = *(const int4*)p;
            int4 c1 = *(const int4*)(p + 4);
            unsigned lo = (unsigned)c0.x | ((unsigned)c0.y << 8) |
                          ((unsigned)c0.z << 16) | ((unsigned)c0.w << 24);
            unsigned hi = (unsigned)c1.x | ((unsigned)c1.y << 8) |
                          ((unsigned)c1.z << 16) | ((unsigned)c1.w << 24);
            catp[jb * 256 + i] = make_uint2(lo, hi);
        }
    }
}

// ---------------------------------------------------------------------------
// One GINE layer, fused: aggregation (8 dst nodes per block) + MLP + 3 LNs +
// residual. Last layer also does the output projection (HID -> 3).
__global__ __launch_bounds__(512) void k_layer(
    const float* __restrict__ h_old, float* __restrict__ h_new,
    const float* __restrict__ ne, const uint2* __restrict__ catp,
    const float* __restrict__ W1, const float* __restrict__ b1,
    const float* __restrict__ g1, const float* __restrict__ bt1,
    const float* __restrict__ W2, const float* __restrict__ b2,
    const float* __restrict__ g2, const float* __restrict__ bt2,
    const float* __restrict__ epsp,
    const float* __restrict__ lng, const float* __restrict__ lnb,
    const float* __restrict__ outW, const float* __restrict__ outb,
    float* __restrict__ dout, int isLast)
{
    __shared__ __align__(16) float sNe[NCATS * HID];   // 32 KB
    __shared__ __align__(16) float sAcc[16 * 8 * 128]; // 64 KB (also GEMM partials)
    __shared__ __align__(16) uint2 sCat[256];          // 2 KB
    __shared__ __align__(16) float sU[8][128];
    __shared__ __align__(16) float sH1[8][128];
    __shared__ __align__(16) float sV[8][128];

    const int t = threadIdx.x;
    const int b = blockIdx.x >> 5;
    const int jb = blockIdx.x & 31;
    const int w = t >> 6, lane = t & 63;
    const float* hb = h_old + (size_t)b * NN * HID;

    // stage ne (f32, 2048 float4) + this block's packed cats
    for (int idx = t; idx < NCATS * HID / 4; idx += 512)
        ((float4*)sNe)[idx] = ((const float4*)ne)[idx];
    if (t < 256) sCat[t] = catp[jb * 256 + t];
    __syncthreads();

    // ---- aggregation: agg[j][d] = sum_i relu(h[i][d] + ne[cat(i,j)][d]) ----
    const int dg = t & 31;   // 4 dims per thread
    const int ig = t >> 5;   // 16 source groups of 16
    float4 acc[8];
    #pragma unroll
    for (int k = 0; k < 8; ++k) acc[k] = make_float4(0.f, 0.f, 0.f, 0.f);

    for (int n = 0; n < 16; ++n) {
        int i = ig * 16 + n;
        float4 hv = *(const float4*)(hb + i * HID + dg * 4);
        uint2 c8 = sCat[i];
        #pragma unroll
        for (int k = 0; k < 8; ++k) {
            unsigned c = ((k < 4 ? (c8.x >> (8 * k)) : (c8.y >> (8 * (k - 4)))) & 255u);
            float4 nv = *(const float4*)&sNe[c * HID + dg * 4];
            acc[k].x += fmaxf(hv.x + nv.x, 0.f);
            acc[k].y += fmaxf(hv.y + nv.y, 0.f);
            acc[k].z += fmaxf(hv.z + nv.z, 0.f);
            acc[k].w += fmaxf(hv.w + nv.w, 0.f);
        }
    }
    #pragma unroll
    for (int k = 0; k < 8; ++k)
        *(float4*)&sAcc[(ig * 8 + k) * 128 + dg * 4] = acc[k];
    __syncthreads();

    // ---- combine partials, u = (1+eps)*h + agg ----
    const float eps1 = 1.0f + epsp[0];
    for (int item = t; item < 1024; item += 512) {
        int r = item >> 7, dd = item & 127;
        float s = 0.f;
        #pragma unroll
        for (int igx = 0; igx < 16; ++igx) s += sAcc[(igx * 8 + r) * 128 + dd];
        sU[r][dd] = eps1 * hb[(jb * 8 + r) * HID + dd] + s;
    }
    __syncthreads();

    // ---- GEMM1: v = u @ W1 + b1 (k-split by 4, 8-row register blocking) ----
    {
        int dd = t & 127, ks = t >> 7;
        float a8[8] = {0.f, 0.f, 0.f, 0.f, 0.f, 0.f, 0.f, 0.f};
        for (int k = ks * 32; k < ks * 32 + 32; ++k) {
            float wv = W1[k * 128 + dd];
            #pragma unroll
            for (int r = 0; r < 8; ++r) a8[r] = fmaf(sU[r][k], wv, a8[r]);
        }
        #pragma unroll
        for (int r = 0; r < 8; ++r) sAcc[(ks * 8 + r) * 128 + dd] = a8[r];
    }
    __syncthreads();
    for (int item = t; item < 1024; item += 512) {
        int r = item >> 7, dd = item & 127;
        sV[r][dd] = b1[dd] + sAcc[r * 128 + dd] + sAcc[(8 + r) * 128 + dd] +
                    sAcc[(16 + r) * 128 + dd] + sAcc[(24 + r) * 128 + dd];
    }
    __syncthreads();

    // ---- LN1 + relu -> sH1 ----
    {
        float a = sV[w][lane], c = sV[w][lane + 64];
        float mean, rs; ln_stats(a, c, mean, rs);
        sH1[w][lane]      = fmaxf((a - mean) * rs * g1[lane]      + bt1[lane],      0.f);
        sH1[w][lane + 64] = fmaxf((c - mean) * rs * g1[lane + 64] + bt1[lane + 64], 0.f);
    }
    __syncthreads();

    // ---- GEMM2: v = h1 @ W2 + b2 ----
    {
        int dd = t & 127, ks = t >> 7;
        float a8[8] = {0.f, 0.f, 0.f, 0.f, 0.f, 0.f, 0.f, 0.f};
        for (int k = ks * 32; k < ks * 32 + 32; ++k) {
            float wv = W2[k * 128 + dd];
            #pragma unroll
            for (int r = 0; r < 8; ++r) a8[r] = fmaf(sH1[r][k], wv, a8[r]);
        }
        #pragma unroll
        for (int r = 0; r < 8; ++r) sAcc[(ks * 8 + r) * 128 + dd] = a8[r];
    }
    __syncthreads();
    for (int item = t; item < 1024; item += 512) {
        int r = item >> 7, dd = item & 127;
        sV[r][dd] = b2[dd] + sAcc[r * 128 + dd] + sAcc[(8 + r) * 128 + dd] +
                    sAcc[(16 + r) * 128 + dd] + sAcc[(24 + r) * 128 + dd];
    }
    __syncthreads();

    // ---- LN2 (g2,bt2) then LN3 (lng,lnb) + relu + residual, in-wave ----
    {
        float a = sV[w][lane], c = sV[w][lane + 64];
        float mean, rs; ln_stats(a, c, mean, rs);
        float y1 = (a - mean) * rs * g2[lane]      + bt2[lane];
        float y2 = (c - mean) * rs * g2[lane + 64] + bt2[lane + 64];

        float mean3, rs3; ln_stats(y1, y2, mean3, rs3);
        int row = jb * 8 + w;
        int grow = b * NN + row;
        float ho1 = hb[row * HID + lane], ho2 = hb[row * HID + lane + 64];
        float z1 = fmaxf((y1 - mean3) * rs3 * lng[lane]      + lnb[lane],      0.f) + ho1;
        float z2 = fmaxf((y2 - mean3) * rs3 * lng[lane + 64] + lnb[lane + 64], 0.f) + ho2;

        if (!isLast) {
            h_new[(size_t)grow * HID + lane]      = z1;
            h_new[(size_t)grow * HID + lane + 64] = z2;
        } else {
            #pragma unroll
            for (int cc = 0; cc < 3; ++cc) {
                float p = z1 * outW[lane * 3 + cc] + z2 * outW[(lane + 64) * 3 + cc];
                #pragma unroll
                for (int m = 32; m; m >>= 1) p += __shfl_xor(p, m);
                if (lane == 0) dout[grow * 3 + cc] = p + outb[cc];
            }
        }
    }
}

// ---------------------------------------------------------------------------
extern "C" void kernel_launch(void* const* d_in, const int* in_sizes, int n_in,
                              void* d_out, int out_size, void* d_ws, size_t ws_size,
                              hipStream_t stream) {
    const float* x     = (const float*)d_in[0];
    const float* emb   = (const float*)d_in[1];
    const float* inW1  = (const float*)d_in[2];
    const float* inb1  = (const float*)d_in[3];
    const float* ing1  = (const float*)d_in[4];
    const float* inbt1 = (const float*)d_in[5];
    const float* inW2  = (const float*)d_in[6];
    const float* inb2  = (const float*)d_in[7];
    const float* ing2  = (const float*)d_in[8];
    const float* inbt2 = (const float*)d_in[9];
    const float* cW1   = (const float*)d_in[10];
    const float* cb1   = (const float*)d_in[11];
    const float* cg1   = (const float*)d_in[12];
    const float* cbt1  = (const float*)d_in[13];
    const float* cW2   = (const float*)d_in[14];
    const float* cb2   = (const float*)d_in[15];
    const float* cg2   = (const float*)d_in[16];
    const float* cbt2  = (const float*)d_in[17];
    const float* ceps  = (const float*)d_in[18];
    const float* lng   = (const float*)d_in[19];
    const float* lnb   = (const float*)d_in[20];
    const float* outW  = (const float*)d_in[21];
    const float* outb  = (const float*)d_in[22];
    const int*   ecat  = (const int*)d_in[25];

    float* ws   = (float*)d_ws;
    float* ne   = ws;                           // 8192 floats
    uint2* catp = (uint2*)(ws + 8192);          // 8192 uint2 (16384 float slots)
    float* hA   = ws + 8192 + 16384;            // B*N*HID
    float* hB   = hA + BB * NN * HID;
    float* out  = (float*)d_out;

    k_setup<<<296, 512, 0, stream>>>(x, emb, inW1, inb1, ing1, inbt1,
                                     inW2, inb2, ing2, inbt2, ecat, ne, catp, hA);

    for (int l = 0; l < 4; ++l) {
        const float* ho = (l & 1) ? hB : hA;
        float*       hn = (l & 1) ? hA : hB;
        k_layer<<<256, 512, 0, stream>>>(
            ho, hn, ne, catp,
            cW1 + l * HID * HID, cb1 + l * HID, cg1 + l * HID, cbt1 + l * HID,
            cW2 + l * HID * HID, cb2 + l * HID, cg2 + l * HID, cbt2 + l * HID,
            ceps + l, lng + l * HID, lnb + l * HID,
            outW, outb, out, (l == 3) ? 1 : 0);
    }
}